// Round 9
// baseline (378.903 us; speedup 1.0000x reference)
//
#include <hip/hip_runtime.h>
#include <hip/hip_bf16.h>

#define B_DIM   1024
#define N_DIM   2048
#define G_DIM   32
#define H1_DIM  2048
#define H2_DIM  512
#define BN_EPS  1e-5f
#define SLOPE   0.05f

typedef short v8s __attribute__((ext_vector_type(8)));
typedef float v4f __attribute__((ext_vector_type(4)));

__device__ __forceinline__ float lrelu_f(float v) { return v >= 0.f ? v : SLOPE * v; }
__device__ __forceinline__ float bf2f(unsigned short u) {
    union { unsigned int i; float f; } c; c.i = ((unsigned int)u) << 16; return c.f;
}
__device__ __forceinline__ unsigned short f2bf(float f) {
    __hip_bfloat16 h = __float2bfloat16(f);
    return *(unsigned short*)&h;
}

// async global->LDS, 16B per lane, linear LDS dest (wave-uniform base + lane*16)
#define GLOAD_LDS16(gp, lp)                                                              \
    __builtin_amdgcn_global_load_lds(                                                    \
        (const __attribute__((address_space(1))) unsigned int*)(gp),                     \
        (__attribute__((address_space(3))) unsigned int*)(lp), 16, 0, 0)

// grid barrier: all NBLK blocks co-resident (LDS/VGPR budget guarantees 2/CU).
// release: threadfence (agent-scope wb/inv) before counting; acquire on exit.
__device__ __forceinline__ void grid_barrier(unsigned int* cnt, unsigned int nblk, int tid) {
    __threadfence();
    __syncthreads();
    if (tid == 0) {
        __hip_atomic_fetch_add(cnt, 1u, __ATOMIC_ACQ_REL, __HIP_MEMORY_SCOPE_AGENT);
        while (__hip_atomic_load(cnt, __ATOMIC_ACQUIRE, __HIP_MEMORY_SCOPE_AGENT) < nblk)
            __builtin_amdgcn_s_sleep(2);
    }
    __syncthreads();
    __threadfence();
}

// ================================================================ prep kernel
// bid < 2048          : group_linear  g[b][n] = lrelu(dot(x[b,n*32:], Wg[n]) + bg[n])
// 2048 <= bid < 3072  : W1 [N][H1] -> W1T [H1][N] bf16, rows scaled by softmax(att_w)
// bid >= 3072         : W2 [H1][H2] -> W2T [H2][H1] bf16
__global__ __launch_bounds__(256) void prep_kernel(
        const float* __restrict__ x, const float* __restrict__ Wg,
        const float* __restrict__ bg, __hip_bfloat16* __restrict__ g,
        const float* __restrict__ W1, const float* __restrict__ W2,
        const float* __restrict__ aw,
        __hip_bfloat16* __restrict__ W1T, __hip_bfloat16* __restrict__ W2T) {
    __shared__ float tile[64][65];
    __shared__ float red[8];
    __shared__ float scl[64];
    int t = threadIdx.x;
    int bid = blockIdx.x;

    if (bid < 2048) {
        int brow = bid >> 4;
        int seg = bid & 15;
        int gl = t >> 1, half = t & 1;
        int n = seg * 128 + gl;
        float4 wv[4];
        const float4* wsrc = (const float4*)(Wg + (size_t)n * 32 + half * 16);
#pragma unroll
        for (int q = 0; q < 4; ++q) wv[q] = wsrc[q];
        float bgv = bg[n];
#pragma unroll
        for (int bb = 0; bb < 8; ++bb) {
            int b = brow * 8 + bb;
            const float4* xr = (const float4*)(x + (size_t)b * (N_DIM * G_DIM) +
                                               (size_t)n * 32 + half * 16);
            float s = 0.f;
#pragma unroll
            for (int q = 0; q < 4; ++q) {
                float4 v = xr[q];
                s += v.x * wv[q].x + v.y * wv[q].y + v.z * wv[q].z + v.w * wv[q].w;
            }
            s += __shfl_xor(s, 1, 64);
            if (half == 0)
                g[(size_t)b * N_DIM + n] = __float2bfloat16(lrelu_f(s + bgv));
        }
        return;
    }

    const float* W;
    __hip_bfloat16* Wt;
    int Kd, Jd, j0, k0;
    bool doScale;
    int tb = bid - 2048;
    if (tb < 1024) {
        W = W1; Wt = W1T; Kd = N_DIM; Jd = H1_DIM;
        j0 = (tb & 31) * 64; k0 = (tb >> 5) * 64; doScale = true;
        float mx = -1e30f;
#pragma unroll
        for (int i = 0; i < 8; ++i) mx = fmaxf(mx, aw[t + i * 256]);
#pragma unroll
        for (int off = 32; off; off >>= 1) mx = fmaxf(mx, __shfl_xor(mx, off, 64));
        if ((t & 63) == 0) red[t >> 6] = mx;
        __syncthreads();
        float M = fmaxf(fmaxf(red[0], red[1]), fmaxf(red[2], red[3]));
        float sm = 0.f;
#pragma unroll
        for (int i = 0; i < 8; ++i) sm += expf(aw[t + i * 256] - M);
#pragma unroll
        for (int off = 32; off; off >>= 1) sm += __shfl_xor(sm, off, 64);
        if ((t & 63) == 0) red[4 + (t >> 6)] = sm;
        __syncthreads();
        float invS = 1.f / (red[4] + red[5] + red[6] + red[7]);
        if (t < 64) scl[t] = expf(aw[k0 + t] - M) * invS;
        __syncthreads();
    } else {
        int b2 = tb - 1024;
        W = W2; Wt = W2T; Kd = H1_DIM; Jd = H2_DIM;
        j0 = (b2 & 7) * 64; k0 = (b2 >> 3) * 64; doScale = false;
    }
#pragma unroll
    for (int p = 0; p < 16; ++p) {
        int r = (t >> 6) + p * 4;
        float v = W[(size_t)(k0 + r) * Jd + j0 + (t & 63)];
        if (doScale) v *= scl[r];
        tile[r][t & 63] = v;
    }
    __syncthreads();
#pragma unroll
    for (int p = 0; p < 8; ++p) {
        int jr = (t >> 5) + p * 8;
        int kc = (t & 31) * 2;
        ushort2 pk;
        pk.x = f2bf(tile[kc][jr]);
        pk.y = f2bf(tile[kc + 1][jr]);
        *(ushort2*)(Wt + (size_t)(j0 + jr) * Kd + k0 + kc) = pk;
    }
}

// ================================================================ fused main (512 blocks, 2/CU)
// Phase 1: GEMM1 64x64 BK=128 (+BN1 partial stats)      [all 512 blocks]
// Phase 2: GEMM2 64x32 BK=128 with BN1 fold (+BN2 stats)[blocks 0..255]
// Phase 3: BN2 finalize + lrelu + dot(Wo) + bo -> out   [all 512, 2 rows each]
__global__ __launch_bounds__(256, 2) void fused_main(
        const __hip_bfloat16* __restrict__ g, const __hip_bfloat16* __restrict__ W1T,
        const __hip_bfloat16* __restrict__ W2T,
        __hip_bfloat16* __restrict__ h1pre, float* __restrict__ h2raw,
        float* __restrict__ ps1, float* __restrict__ pq1,
        float* __restrict__ ps2, float* __restrict__ pq2,
        const float* __restrict__ gamma1, const float* __restrict__ beta1,
        const float* __restrict__ gamma2, const float* __restrict__ beta2,
        const float* __restrict__ Wo, const float* __restrict__ bo,
        float* __restrict__ out, unsigned int* __restrict__ cnts) {
    __shared__ __align__(16) char smem[66560];
    int tid = threadIdx.x, lane = tid & 63, wave = tid >> 6;
    int bid = blockIdx.x;
    int l15 = lane & 15, kq = lane >> 4;

    // ================= Phase 1: GEMM1 + BN1 partial stats =================
    {
        __hip_bfloat16 (*A_s)[64 * 128] = (__hip_bfloat16(*)[64 * 128])(smem);
        __hip_bfloat16 (*B_s)[64 * 128] = (__hip_bfloat16(*)[64 * 128])(smem + 32768);
        float* rs1 = (float*)(smem + 65536);   // [2][64]
        float* rq1 = (float*)(smem + 66048);

        int wg = (bid & 7) * 64 + (bid >> 3);      // XCD-aware bijective swizzle (512)
        int bx = wg & 15, by = wg >> 4;            // 16 row-tiles x 32 col-tiles
        int wr = wave >> 1, wc = wave & 1;
        int rbase = bx * 64, cbase = by * 64;

        v4f acc[2][2] = {};

        auto stage = [&](int buf, int kt) {
            int k0 = kt << 7;
#pragma unroll
            for (int i = 0; i < 4; ++i) {
                int s = tid + i * 256;
                int row = s >> 4, cg2 = (s & 15) ^ (row & 15);
                GLOAD_LDS16(g + (size_t)(rbase + row) * N_DIM + k0 + cg2 * 8,
                            (char*)A_s[buf] + s * 16);
            }
#pragma unroll
            for (int i = 0; i < 4; ++i) {
                int s = tid + i * 256;
                int row = s >> 4, cg2 = (s & 15) ^ (row & 15);
                GLOAD_LDS16(W1T + (size_t)(cbase + row) * N_DIM + k0 + cg2 * 8,
                            (char*)B_s[buf] + s * 16);
            }
        };

        stage(0, 0);
        __syncthreads();
        int cur = 0;
        for (int kt = 0; kt < 16; ++kt) {
            if (kt + 1 < 16) stage(cur ^ 1, kt + 1);
#pragma unroll
            for (int kc = 0; kc < 4; ++kc) {
                v8s af[2], bfv[2];
#pragma unroll
                for (int m = 0; m < 2; ++m) {
                    int row = wr * 32 + m * 16 + l15;
                    int off = row * 256 + (((kc * 4 + kq) ^ (row & 15)) << 4);
                    af[m] = *(const v8s*)((const char*)A_s[cur] + off);
                }
#pragma unroll
                for (int n = 0; n < 2; ++n) {
                    int row = wc * 32 + n * 16 + l15;
                    int off = row * 256 + (((kc * 4 + kq) ^ (row & 15)) << 4);
                    bfv[n] = *(const v8s*)((const char*)B_s[cur] + off);
                }
                __builtin_amdgcn_s_setprio(1);
#pragma unroll
                for (int m = 0; m < 2; ++m)
#pragma unroll
                    for (int n = 0; n < 2; ++n)
                        acc[m][n] = __builtin_amdgcn_mfma_f32_16x16x32_bf16(af[m], bfv[n],
                                                                            acc[m][n], 0, 0, 0);
                __builtin_amdgcn_s_setprio(0);
            }
            __syncthreads();
            cur ^= 1;
        }

        int crow = kq * 4;
#pragma unroll
        for (int m = 0; m < 2; ++m)
#pragma unroll
            for (int n = 0; n < 2; ++n) {
                int r = rbase + wr * 32 + m * 16 + crow;
                int c = cbase + wc * 32 + n * 16 + l15;
#pragma unroll
                for (int i = 0; i < 4; ++i)
                    h1pre[(size_t)(r + i) * H1_DIM + c] = __float2bfloat16(acc[m][n][i]);
            }

        float cs[2], cq[2];
#pragma unroll
        for (int n = 0; n < 2; ++n) {
            cs[n] = 0.f; cq[n] = 0.f;
#pragma unroll
            for (int m = 0; m < 2; ++m)
#pragma unroll
                for (int i = 0; i < 4; ++i) {
                    float v = acc[m][n][i];
                    cs[n] += v; cq[n] += v * v;
                }
#pragma unroll
            for (int off = 16; off <= 32; off <<= 1) {
                cs[n] += __shfl_xor(cs[n], off, 64);
                cq[n] += __shfl_xor(cq[n], off, 64);
            }
        }
        if (lane < 16) {
#pragma unroll
            for (int n = 0; n < 2; ++n) {
                rs1[wr * 64 + wc * 32 + n * 16 + lane] = cs[n];
                rq1[wr * 64 + wc * 32 + n * 16 + lane] = cq[n];
            }
        }
        __syncthreads();
        if (tid < 64) {
            ps1[(size_t)bx * H1_DIM + cbase + tid] = rs1[tid] + rs1[64 + tid];
            pq1[(size_t)bx * H1_DIM + cbase + tid] = rq1[tid] + rq1[64 + tid];
        }
    }

    grid_barrier(&cnts[0], 512u, tid);

    // ================= Phase 2: GEMM2 with BN1 folded (blocks 0..255) =================
    if (bid < 256) {
        float* scl = (float*)(smem);              // [2048]
        float* shf = (float*)(smem + 8192);       // [2048]
        __hip_bfloat16 (*A2)[64 * 128] = (__hip_bfloat16(*)[64 * 128])(smem + 16384);
        __hip_bfloat16 (*B2)[32 * 128] = (__hip_bfloat16(*)[32 * 128])(smem + 49152);
        float* rs2 = (float*)(smem + 65536);      // [4][32]
        float* rq2 = (float*)(smem + 66048);

        // BN1 finalize (block-redundant)
#pragma unroll
        for (int p = 0; p < 8; ++p) {
            int c = tid + p * 256;
            float s = 0.f, q = 0.f;
#pragma unroll
            for (int i = 0; i < 16; ++i) {
                s += ps1[i * H1_DIM + c];
                q += pq1[i * H1_DIM + c];
            }
            float mu = s * (1.f / B_DIM);
            float var = fmaxf(q * (1.f / B_DIM) - mu * mu, 0.f);
            float rsv = rsqrtf(var + BN_EPS);
            float sc = rsv * gamma1[c];
            scl[c] = sc;
            shf[c] = beta1[c] - mu * sc;
        }
        __syncthreads();

        int wg = (bid & 7) * 32 + (bid >> 3);
        int bxx = wg & 15, byy = wg >> 4;
        int rb = bxx * 64, cb = byy * 32;

        v4f acc2[2] = {};

        auto stageA2 = [&](int buf, int kt) {
            int k0 = kt << 7;
#pragma unroll
            for (int i = 0; i < 4; ++i) {
                int s = tid + i * 256;
                int row = s >> 4, cc = s & 15;
                v8s hv = *(const v8s*)(h1pre + (size_t)(rb + row) * H1_DIM + k0 + cc * 8);
                int kk = k0 + cc * 8;
                float4 s0 = *(const float4*)&scl[kk];
                float4 s1 = *(const float4*)&scl[kk + 4];
                float4 f0 = *(const float4*)&shf[kk];
                float4 f1 = *(const float4*)&shf[kk + 4];
                v8s pk;
                pk[0] = (short)f2bf(lrelu_f(bf2f((unsigned short)hv[0]) * s0.x + f0.x));
                pk[1] = (short)f2bf(lrelu_f(bf2f((unsigned short)hv[1]) * s0.y + f0.y));
                pk[2] = (short)f2bf(lrelu_f(bf2f((unsigned short)hv[2]) * s0.z + f0.z));
                pk[3] = (short)f2bf(lrelu_f(bf2f((unsigned short)hv[3]) * s0.w + f0.w));
                pk[4] = (short)f2bf(lrelu_f(bf2f((unsigned short)hv[4]) * s1.x + f1.x));
                pk[5] = (short)f2bf(lrelu_f(bf2f((unsigned short)hv[5]) * s1.y + f1.y));
                pk[6] = (short)f2bf(lrelu_f(bf2f((unsigned short)hv[6]) * s1.z + f1.z));
                pk[7] = (short)f2bf(lrelu_f(bf2f((unsigned short)hv[7]) * s1.w + f1.w));
                *(v8s*)((char*)A2[buf] + (row * 16 + (cc ^ (row & 15))) * 16) = pk;
            }
        };
        auto stageB2 = [&](int buf, int kt) {
            int k0 = kt << 7;
#pragma unroll
            for (int i = 0; i < 2; ++i) {
                int s = tid + i * 256;
                int row = s >> 4, cg2 = (s & 15) ^ (row & 15);
                GLOAD_LDS16(W2T + (size_t)(cb + row) * H1_DIM + k0 + cg2 * 8,
                            (char*)B2[buf] + s * 16);
            }
        };

        stageB2(0, 0);
        stageA2(0, 0);
        __syncthreads();
        int cur = 0;
        for (int kt = 0; kt < 16; ++kt) {
            if (kt + 1 < 16) { stageB2(cur ^ 1, kt + 1); stageA2(cur ^ 1, kt + 1); }
#pragma unroll
            for (int kc = 0; kc < 4; ++kc) {
                int arow = wave * 16 + l15;
                v8s af = *(const v8s*)((const char*)A2[cur] +
                                       arow * 256 + (((kc * 4 + kq) ^ (arow & 15)) << 4));
                v8s bf0 = *(const v8s*)((const char*)B2[cur] +
                                        l15 * 256 + (((kc * 4 + kq) ^ (l15 & 15)) << 4));
                int brow1 = 16 + l15;
                v8s bf1 = *(const v8s*)((const char*)B2[cur] +
                                        brow1 * 256 + (((kc * 4 + kq) ^ (brow1 & 15)) << 4));
                __builtin_amdgcn_s_setprio(1);
                acc2[0] = __builtin_amdgcn_mfma_f32_16x16x32_bf16(af, bf0, acc2[0], 0, 0, 0);
                acc2[1] = __builtin_amdgcn_mfma_f32_16x16x32_bf16(af, bf1, acc2[1], 0, 0, 0);
                __builtin_amdgcn_s_setprio(0);
            }
            __syncthreads();
            cur ^= 1;
        }

        int crow = kq * 4;
#pragma unroll
        for (int n = 0; n < 2; ++n) {
            int r = rb + wave * 16 + crow;
            int c = cb + n * 16 + l15;
#pragma unroll
            for (int i = 0; i < 4; ++i)
                h2raw[(size_t)(r + i) * H2_DIM + c] = acc2[n][i];
        }

        float cs[2], cq[2];
#pragma unroll
        for (int n = 0; n < 2; ++n) {
            cs[n] = 0.f; cq[n] = 0.f;
#pragma unroll
            for (int i = 0; i < 4; ++i) {
                float v = acc2[n][i];
                cs[n] += v; cq[n] += v * v;
            }
#pragma unroll
            for (int off = 16; off <= 32; off <<= 1) {
                cs[n] += __shfl_xor(cs[n], off, 64);
                cq[n] += __shfl_xor(cq[n], off, 64);
            }
        }
        if (lane < 16) {
#pragma unroll
            for (int n = 0; n < 2; ++n) {
                rs2[wave * 32 + n * 16 + lane] = cs[n];
                rq2[wave * 32 + n * 16 + lane] = cq[n];
            }
        }
        __syncthreads();
        if (tid < 32) {
            float s = 0.f, q = 0.f;
#pragma unroll
            for (int w = 0; w < 4; ++w) { s += rs2[w * 32 + tid]; q += rq2[w * 32 + tid]; }
            ps2[(size_t)bxx * H2_DIM + cb + tid] = s;
            pq2[(size_t)bxx * H2_DIM + cb + tid] = q;
        }
    }

    grid_barrier(&cnts[1], 512u, tid);

    // ================= Phase 3: BN2 finalize + lrelu + dot (2 rows/block) =================
    {
        float* scl2 = (float*)(smem);             // [512]
        float* shf2 = (float*)(smem + 2048);      // [512]
        float* red  = (float*)(smem + 4096);      // [4]
#pragma unroll
        for (int p = 0; p < 2; ++p) {
            int c = tid + p * 256;
            float s = 0.f, q = 0.f;
#pragma unroll
            for (int i = 0; i < 16; ++i) {
                s += ps2[i * H2_DIM + c];
                q += pq2[i * H2_DIM + c];
            }
            float mu = s * (1.f / B_DIM);
            float var = fmaxf(q * (1.f / B_DIM) - mu * mu, 0.f);
            float rsv = rsqrtf(var + BN_EPS);
            float sc = rsv * gamma2[c];
            scl2[c] = sc;
            shf2[c] = beta2[c] - mu * sc;
        }
        __syncthreads();
#pragma unroll
        for (int rr = 0; rr < 2; ++rr) {
            int b = bid * 2 + rr;
            float s = 0.f;
#pragma unroll
            for (int p = 0; p < 2; ++p) {
                int j = tid + p * 256;
                float v = lrelu_f(h2raw[(size_t)b * H2_DIM + j] * scl2[j] + shf2[j]);
                s += v * Wo[j];
            }
#pragma unroll
            for (int off = 32; off; off >>= 1) s += __shfl_down(s, off, 64);
            if (lane == 0) red[wave] = s;
            __syncthreads();
            if (tid == 0) out[b] = red[0] + red[1] + red[2] + red[3] + bo[0];
            __syncthreads();
        }
    }
}

// ================================================================ host
extern "C" void kernel_launch(void* const* d_in, const int* in_sizes, int n_in,
                              void* d_out, int out_size, void* d_ws, size_t ws_size,
                              hipStream_t stream) {
    const float* x     = (const float*)d_in[0];
    const float* Wg    = (const float*)d_in[1];
    const float* bg    = (const float*)d_in[2];
    const float* att_w = (const float*)d_in[3];
    const float* W1    = (const float*)d_in[4];
    const float* gamma1 = (const float*)d_in[6];
    const float* beta1  = (const float*)d_in[7];
    const float* W2    = (const float*)d_in[8];
    const float* gamma2 = (const float*)d_in[10];
    const float* beta2  = (const float*)d_in[11];
    const float* Wo    = (const float*)d_in[12];
    const float* bo    = (const float*)d_in[13];
    float* out = (float*)d_out;

    char* ws = (char*)d_ws;
    size_t off = 0;
    auto alloc = [&](size_t bytes) {
        void* p = ws + off;
        off = (off + bytes + 255) & ~(size_t)255;
        return p;
    };
    __hip_bfloat16* W1T   = (__hip_bfloat16*)alloc((size_t)H1_DIM * N_DIM * 2);
    __hip_bfloat16* W2T   = (__hip_bfloat16*)alloc((size_t)H2_DIM * H1_DIM * 2);
    __hip_bfloat16* g     = (__hip_bfloat16*)alloc((size_t)B_DIM * N_DIM * 2);
    __hip_bfloat16* h1pre = (__hip_bfloat16*)alloc((size_t)B_DIM * H1_DIM * 2);
    float*          h2raw = (float*)alloc((size_t)B_DIM * H2_DIM * 4);
    float*          ps1   = (float*)alloc(16 * H1_DIM * 4);
    float*          pq1   = (float*)alloc(16 * H1_DIM * 4);
    float*          ps2   = (float*)alloc(16 * H2_DIM * 4);
    float*          pq2   = (float*)alloc(16 * H2_DIM * 4);
    unsigned int*   cnts  = (unsigned int*)alloc(256);
    (void)ws_size; (void)in_sizes; (void)n_in; (void)out_size;

    // reset grid-barrier counters (stream-ordered, graph-capture legal, deterministic)
    hipMemsetAsync(cnts, 0, 8, stream);
    // 1. prep: group_linear (2048 blocks) + softmax/W1T (1024) + W2T (256)
    prep_kernel<<<dim3(2048 + 1024 + 256), 256, 0, stream>>>(x, Wg, bg, g,
                                                             W1, W2, att_w, W1T, W2T);
    // 2. fused: GEMM1+stats -> barrier -> GEMM2(+BN1)+stats -> barrier -> BN2+dot
    fused_main<<<dim3(512), 256, 0, stream>>>(g, W1T, W2T, h1pre, h2raw,
                                              ps1, pq1, ps2, pq2,
                                              gamma1, beta1, gamma2, beta2,
                                              Wo, bo, out, cnts);
}

// Round 10
// 216.051 us; speedup vs baseline: 1.7538x; 1.7538x over previous
//
#include <hip/hip_runtime.h>
#include <hip/hip_bf16.h>

#define B_DIM   1024
#define N_DIM   2048
#define G_DIM   32
#define H1_DIM  2048
#define H2_DIM  512
#define BN_EPS  1e-5f
#define SLOPE   0.05f

typedef short v8s __attribute__((ext_vector_type(8)));
typedef float v4f __attribute__((ext_vector_type(4)));

__device__ __forceinline__ float lrelu_f(float v) { return v >= 0.f ? v : SLOPE * v; }
__device__ __forceinline__ float bf2f(unsigned short u) {
    union { unsigned int i; float f; } c; c.i = ((unsigned int)u) << 16; return c.f;
}
__device__ __forceinline__ unsigned short f2bf(float f) {
    __hip_bfloat16 h = __float2bfloat16(f);
    return *(unsigned short*)&h;
}

// async global->LDS, 16B per lane, linear LDS dest (wave-uniform base + lane*16)
#define GLOAD_LDS16(gp, lp)                                                              \
    __builtin_amdgcn_global_load_lds(                                                    \
        (const __attribute__((address_space(1))) unsigned int*)(gp),                     \
        (__attribute__((address_space(3))) unsigned int*)(lp), 16, 0, 0)

// grid barrier: all NBLK blocks co-resident (LDS 66.5KB x 2/CU, VGPR<=256).
// Count in with RELEASE add (one writeback); spin with RELAXED loads (NO
// per-poll cache invalidate -- round 9's bug) + s_sleep backoff; one acquire
// fence after release so we observe other blocks' writes.
__device__ __forceinline__ void grid_barrier(unsigned int* cnt, unsigned int nblk, int tid) {
    __syncthreads();
    if (tid == 0) {
        __hip_atomic_fetch_add(cnt, 1u, __ATOMIC_RELEASE, __HIP_MEMORY_SCOPE_AGENT);
        while (__hip_atomic_load(cnt, __ATOMIC_RELAXED, __HIP_MEMORY_SCOPE_AGENT) < nblk)
            __builtin_amdgcn_s_sleep(16);
    }
    __syncthreads();
    __threadfence();   // single acquire: invalidate caches once, see peers' data
}

// ================================================================ prep kernel
// bid < 2048          : group_linear  g[b][n] = lrelu(dot(x[b,n*32:], Wg[n]) + bg[n])
// 2048 <= bid < 3072  : W1 [N][H1] -> W1T [H1][N] bf16, rows scaled by softmax(att_w)
// bid >= 3072         : W2 [H1][H2] -> W2T [H2][H1] bf16
__global__ __launch_bounds__(256) void prep_kernel(
        const float* __restrict__ x, const float* __restrict__ Wg,
        const float* __restrict__ bg, __hip_bfloat16* __restrict__ g,
        const float* __restrict__ W1, const float* __restrict__ W2,
        const float* __restrict__ aw,
        __hip_bfloat16* __restrict__ W1T, __hip_bfloat16* __restrict__ W2T) {
    __shared__ float tile[64][65];
    __shared__ float red[8];
    __shared__ float scl[64];
    int t = threadIdx.x;
    int bid = blockIdx.x;

    if (bid < 2048) {
        int brow = bid >> 4;
        int seg = bid & 15;
        int gl = t >> 1, half = t & 1;
        int n = seg * 128 + gl;
        float4 wv[4];
        const float4* wsrc = (const float4*)(Wg + (size_t)n * 32 + half * 16);
#pragma unroll
        for (int q = 0; q < 4; ++q) wv[q] = wsrc[q];
        float bgv = bg[n];
#pragma unroll
        for (int bb = 0; bb < 8; ++bb) {
            int b = brow * 8 + bb;
            const float4* xr = (const float4*)(x + (size_t)b * (N_DIM * G_DIM) +
                                               (size_t)n * 32 + half * 16);
            float s = 0.f;
#pragma unroll
            for (int q = 0; q < 4; ++q) {
                float4 v = xr[q];
                s += v.x * wv[q].x + v.y * wv[q].y + v.z * wv[q].z + v.w * wv[q].w;
            }
            s += __shfl_xor(s, 1, 64);
            if (half == 0)
                g[(size_t)b * N_DIM + n] = __float2bfloat16(lrelu_f(s + bgv));
        }
        return;
    }

    const float* W;
    __hip_bfloat16* Wt;
    int Kd, Jd, j0, k0;
    bool doScale;
    int tb = bid - 2048;
    if (tb < 1024) {
        W = W1; Wt = W1T; Kd = N_DIM; Jd = H1_DIM;
        j0 = (tb & 31) * 64; k0 = (tb >> 5) * 64; doScale = true;
        float mx = -1e30f;
#pragma unroll
        for (int i = 0; i < 8; ++i) mx = fmaxf(mx, aw[t + i * 256]);
#pragma unroll
        for (int off = 32; off; off >>= 1) mx = fmaxf(mx, __shfl_xor(mx, off, 64));
        if ((t & 63) == 0) red[t >> 6] = mx;
        __syncthreads();
        float M = fmaxf(fmaxf(red[0], red[1]), fmaxf(red[2], red[3]));
        float sm = 0.f;
#pragma unroll
        for (int i = 0; i < 8; ++i) sm += expf(aw[t + i * 256] - M);
#pragma unroll
        for (int off = 32; off; off >>= 1) sm += __shfl_xor(sm, off, 64);
        if ((t & 63) == 0) red[4 + (t >> 6)] = sm;
        __syncthreads();
        float invS = 1.f / (red[4] + red[5] + red[6] + red[7]);
        if (t < 64) scl[t] = expf(aw[k0 + t] - M) * invS;
        __syncthreads();
    } else {
        int b2 = tb - 1024;
        W = W2; Wt = W2T; Kd = H1_DIM; Jd = H2_DIM;
        j0 = (b2 & 7) * 64; k0 = (b2 >> 3) * 64; doScale = false;
    }
#pragma unroll
    for (int p = 0; p < 16; ++p) {
        int r = (t >> 6) + p * 4;
        float v = W[(size_t)(k0 + r) * Jd + j0 + (t & 63)];
        if (doScale) v *= scl[r];
        tile[r][t & 63] = v;
    }
    __syncthreads();
#pragma unroll
    for (int p = 0; p < 8; ++p) {
        int jr = (t >> 5) + p * 8;
        int kc = (t & 31) * 2;
        ushort2 pk;
        pk.x = f2bf(tile[kc][jr]);
        pk.y = f2bf(tile[kc + 1][jr]);
        *(ushort2*)(Wt + (size_t)(j0 + jr) * Kd + k0 + kc) = pk;
    }
}

// ================================================================ fused main (512 blocks, 2/CU)
// Phase 1: GEMM1 64x64 BK=128 (+BN1 partial stats)      [all 512 blocks]
// Phase 2: GEMM2 64x32 BK=128 with BN1 fold (+BN2 stats)[blocks 0..255]
// Phase 3: BN2 finalize + lrelu + dot(Wo) + bo -> out   [all 512, 2 rows each]
__global__ __launch_bounds__(256, 2) void fused_main(
        const __hip_bfloat16* __restrict__ g, const __hip_bfloat16* __restrict__ W1T,
        const __hip_bfloat16* __restrict__ W2T,
        __hip_bfloat16* __restrict__ h1pre, float* __restrict__ h2raw,
        float* __restrict__ ps1, float* __restrict__ pq1,
        float* __restrict__ ps2, float* __restrict__ pq2,
        const float* __restrict__ gamma1, const float* __restrict__ beta1,
        const float* __restrict__ gamma2, const float* __restrict__ beta2,
        const float* __restrict__ Wo, const float* __restrict__ bo,
        float* __restrict__ out, unsigned int* __restrict__ cnts) {
    __shared__ __align__(16) char smem[66560];
    int tid = threadIdx.x, lane = tid & 63, wave = tid >> 6;
    int bid = blockIdx.x;
    int l15 = lane & 15, kq = lane >> 4;

    // ================= Phase 1: GEMM1 + BN1 partial stats =================
    {
        __hip_bfloat16 (*A_s)[64 * 128] = (__hip_bfloat16(*)[64 * 128])(smem);
        __hip_bfloat16 (*B_s)[64 * 128] = (__hip_bfloat16(*)[64 * 128])(smem + 32768);
        float* rs1 = (float*)(smem + 65536);   // [2][64]
        float* rq1 = (float*)(smem + 66048);

        int wg = (bid & 7) * 64 + (bid >> 3);      // XCD-aware bijective swizzle (512)
        int bx = wg & 15, by = wg >> 4;            // 16 row-tiles x 32 col-tiles
        int wr = wave >> 1, wc = wave & 1;
        int rbase = bx * 64, cbase = by * 64;

        v4f acc[2][2] = {};

        auto stage = [&](int buf, int kt) {
            int k0 = kt << 7;
#pragma unroll
            for (int i = 0; i < 4; ++i) {
                int s = tid + i * 256;
                int row = s >> 4, cg2 = (s & 15) ^ (row & 15);
                GLOAD_LDS16(g + (size_t)(rbase + row) * N_DIM + k0 + cg2 * 8,
                            (char*)A_s[buf] + s * 16);
            }
#pragma unroll
            for (int i = 0; i < 4; ++i) {
                int s = tid + i * 256;
                int row = s >> 4, cg2 = (s & 15) ^ (row & 15);
                GLOAD_LDS16(W1T + (size_t)(cbase + row) * N_DIM + k0 + cg2 * 8,
                            (char*)B_s[buf] + s * 16);
            }
        };

        stage(0, 0);
        __syncthreads();
        int cur = 0;
        for (int kt = 0; kt < 16; ++kt) {
            if (kt + 1 < 16) stage(cur ^ 1, kt + 1);
#pragma unroll
            for (int kc = 0; kc < 4; ++kc) {
                v8s af[2], bfv[2];
#pragma unroll
                for (int m = 0; m < 2; ++m) {
                    int row = wr * 32 + m * 16 + l15;
                    int off = row * 256 + (((kc * 4 + kq) ^ (row & 15)) << 4);
                    af[m] = *(const v8s*)((const char*)A_s[cur] + off);
                }
#pragma unroll
                for (int n = 0; n < 2; ++n) {
                    int row = wc * 32 + n * 16 + l15;
                    int off = row * 256 + (((kc * 4 + kq) ^ (row & 15)) << 4);
                    bfv[n] = *(const v8s*)((const char*)B_s[cur] + off);
                }
                __builtin_amdgcn_s_setprio(1);
#pragma unroll
                for (int m = 0; m < 2; ++m)
#pragma unroll
                    for (int n = 0; n < 2; ++n)
                        acc[m][n] = __builtin_amdgcn_mfma_f32_16x16x32_bf16(af[m], bfv[n],
                                                                            acc[m][n], 0, 0, 0);
                __builtin_amdgcn_s_setprio(0);
            }
            __syncthreads();
            cur ^= 1;
        }

        int crow = kq * 4;
#pragma unroll
        for (int m = 0; m < 2; ++m)
#pragma unroll
            for (int n = 0; n < 2; ++n) {
                int r = rbase + wr * 32 + m * 16 + crow;
                int c = cbase + wc * 32 + n * 16 + l15;
#pragma unroll
                for (int i = 0; i < 4; ++i)
                    h1pre[(size_t)(r + i) * H1_DIM + c] = __float2bfloat16(acc[m][n][i]);
            }

        float cs[2], cq[2];
#pragma unroll
        for (int n = 0; n < 2; ++n) {
            cs[n] = 0.f; cq[n] = 0.f;
#pragma unroll
            for (int m = 0; m < 2; ++m)
#pragma unroll
                for (int i = 0; i < 4; ++i) {
                    float v = acc[m][n][i];
                    cs[n] += v; cq[n] += v * v;
                }
#pragma unroll
            for (int off = 16; off <= 32; off <<= 1) {
                cs[n] += __shfl_xor(cs[n], off, 64);
                cq[n] += __shfl_xor(cq[n], off, 64);
            }
        }
        if (lane < 16) {
#pragma unroll
            for (int n = 0; n < 2; ++n) {
                rs1[wr * 64 + wc * 32 + n * 16 + lane] = cs[n];
                rq1[wr * 64 + wc * 32 + n * 16 + lane] = cq[n];
            }
        }
        __syncthreads();
        if (tid < 64) {
            ps1[(size_t)bx * H1_DIM + cbase + tid] = rs1[tid] + rs1[64 + tid];
            pq1[(size_t)bx * H1_DIM + cbase + tid] = rq1[tid] + rq1[64 + tid];
        }
    }

    grid_barrier(&cnts[0], 512u, tid);

    // ================= Phase 2: GEMM2 with BN1 folded (blocks 0..255) =================
    if (bid < 256) {
        float* scl = (float*)(smem);              // [2048]
        float* shf = (float*)(smem + 8192);       // [2048]
        __hip_bfloat16 (*A2)[64 * 128] = (__hip_bfloat16(*)[64 * 128])(smem + 16384);
        __hip_bfloat16 (*B2)[32 * 128] = (__hip_bfloat16(*)[32 * 128])(smem + 49152);
        float* rs2 = (float*)(smem + 65536);      // [4][32]
        float* rq2 = (float*)(smem + 66048);

        // BN1 finalize (block-redundant)
#pragma unroll
        for (int p = 0; p < 8; ++p) {
            int c = tid + p * 256;
            float s = 0.f, q = 0.f;
#pragma unroll
            for (int i = 0; i < 16; ++i) {
                s += ps1[i * H1_DIM + c];
                q += pq1[i * H1_DIM + c];
            }
            float mu = s * (1.f / B_DIM);
            float var = fmaxf(q * (1.f / B_DIM) - mu * mu, 0.f);
            float rsv = rsqrtf(var + BN_EPS);
            float sc = rsv * gamma1[c];
            scl[c] = sc;
            shf[c] = beta1[c] - mu * sc;
        }
        __syncthreads();

        int wg = (bid & 7) * 32 + (bid >> 3);
        int bxx = wg & 15, byy = wg >> 4;
        int rb = bxx * 64, cb = byy * 32;

        v4f acc2[2] = {};

        auto stageA2 = [&](int buf, int kt) {
            int k0 = kt << 7;
#pragma unroll
            for (int i = 0; i < 4; ++i) {
                int s = tid + i * 256;
                int row = s >> 4, cc = s & 15;
                v8s hv = *(const v8s*)(h1pre + (size_t)(rb + row) * H1_DIM + k0 + cc * 8);
                int kk = k0 + cc * 8;
                float4 s0 = *(const float4*)&scl[kk];
                float4 s1 = *(const float4*)&scl[kk + 4];
                float4 f0 = *(const float4*)&shf[kk];
                float4 f1 = *(const float4*)&shf[kk + 4];
                v8s pk;
                pk[0] = (short)f2bf(lrelu_f(bf2f((unsigned short)hv[0]) * s0.x + f0.x));
                pk[1] = (short)f2bf(lrelu_f(bf2f((unsigned short)hv[1]) * s0.y + f0.y));
                pk[2] = (short)f2bf(lrelu_f(bf2f((unsigned short)hv[2]) * s0.z + f0.z));
                pk[3] = (short)f2bf(lrelu_f(bf2f((unsigned short)hv[3]) * s0.w + f0.w));
                pk[4] = (short)f2bf(lrelu_f(bf2f((unsigned short)hv[4]) * s1.x + f1.x));
                pk[5] = (short)f2bf(lrelu_f(bf2f((unsigned short)hv[5]) * s1.y + f1.y));
                pk[6] = (short)f2bf(lrelu_f(bf2f((unsigned short)hv[6]) * s1.z + f1.z));
                pk[7] = (short)f2bf(lrelu_f(bf2f((unsigned short)hv[7]) * s1.w + f1.w));
                *(v8s*)((char*)A2[buf] + (row * 16 + (cc ^ (row & 15))) * 16) = pk;
            }
        };
        auto stageB2 = [&](int buf, int kt) {
            int k0 = kt << 7;
#pragma unroll
            for (int i = 0; i < 2; ++i) {
                int s = tid + i * 256;
                int row = s >> 4, cg2 = (s & 15) ^ (row & 15);
                GLOAD_LDS16(W2T + (size_t)(cb + row) * H1_DIM + k0 + cg2 * 8,
                            (char*)B2[buf] + s * 16);
            }
        };

        stageB2(0, 0);
        stageA2(0, 0);
        __syncthreads();
        int cur = 0;
        for (int kt = 0; kt < 16; ++kt) {
            if (kt + 1 < 16) { stageB2(cur ^ 1, kt + 1); stageA2(cur ^ 1, kt + 1); }
#pragma unroll
            for (int kc = 0; kc < 4; ++kc) {
                int arow = wave * 16 + l15;
                v8s af = *(const v8s*)((const char*)A2[cur] +
                                       arow * 256 + (((kc * 4 + kq) ^ (arow & 15)) << 4));
                v8s bf0 = *(const v8s*)((const char*)B2[cur] +
                                        l15 * 256 + (((kc * 4 + kq) ^ (l15 & 15)) << 4));
                int brow1 = 16 + l15;
                v8s bf1 = *(const v8s*)((const char*)B2[cur] +
                                        brow1 * 256 + (((kc * 4 + kq) ^ (brow1 & 15)) << 4));
                __builtin_amdgcn_s_setprio(1);
                acc2[0] = __builtin_amdgcn_mfma_f32_16x16x32_bf16(af, bf0, acc2[0], 0, 0, 0);
                acc2[1] = __builtin_amdgcn_mfma_f32_16x16x32_bf16(af, bf1, acc2[1], 0, 0, 0);
                __builtin_amdgcn_s_setprio(0);
            }
            __syncthreads();
            cur ^= 1;
        }

        int crow = kq * 4;
#pragma unroll
        for (int n = 0; n < 2; ++n) {
            int r = rb + wave * 16 + crow;
            int c = cb + n * 16 + l15;
#pragma unroll
            for (int i = 0; i < 4; ++i)
                h2raw[(size_t)(r + i) * H2_DIM + c] = acc2[n][i];
        }

        float cs[2], cq[2];
#pragma unroll
        for (int n = 0; n < 2; ++n) {
            cs[n] = 0.f; cq[n] = 0.f;
#pragma unroll
            for (int i = 0; i < 4; ++i) {
                float v = acc2[n][i];
                cs[n] += v; cq[n] += v * v;
            }
#pragma unroll
            for (int off = 16; off <= 32; off <<= 1) {
                cs[n] += __shfl_xor(cs[n], off, 64);
                cq[n] += __shfl_xor(cq[n], off, 64);
            }
        }
        if (lane < 16) {
#pragma unroll
            for (int n = 0; n < 2; ++n) {
                rs2[wave * 32 + n * 16 + lane] = cs[n];
                rq2[wave * 32 + n * 16 + lane] = cq[n];
            }
        }
        __syncthreads();
        if (tid < 32) {
            float s = 0.f, q = 0.f;
#pragma unroll
            for (int w = 0; w < 4; ++w) { s += rs2[w * 32 + tid]; q += rq2[w * 32 + tid]; }
            ps2[(size_t)bxx * H2_DIM + cb + tid] = s;
            pq2[(size_t)bxx * H2_DIM + cb + tid] = q;
        }
    }

    grid_barrier(&cnts[1], 512u, tid);

    // ================= Phase 3: BN2 finalize + lrelu + dot (2 rows/block) =================
    {
        float* scl2 = (float*)(smem);             // [512]
        float* shf2 = (float*)(smem + 2048);      // [512]
        float* red  = (float*)(smem + 4096);      // [4]
#pragma unroll
        for (int p = 0; p < 2; ++p) {
            int c = tid + p * 256;
            float s = 0.f, q = 0.f;
#pragma unroll
            for (int i = 0; i < 16; ++i) {
                s += ps2[i * H2_DIM + c];
                q += pq2[i * H2_DIM + c];
            }
            float mu = s * (1.f / B_DIM);
            float var = fmaxf(q * (1.f / B_DIM) - mu * mu, 0.f);
            float rsv = rsqrtf(var + BN_EPS);
            float sc = rsv * gamma2[c];
            scl2[c] = sc;
            shf2[c] = beta2[c] - mu * sc;
        }
        __syncthreads();
#pragma unroll
        for (int rr = 0; rr < 2; ++rr) {
            int b = bid * 2 + rr;
            float s = 0.f;
#pragma unroll
            for (int p = 0; p < 2; ++p) {
                int j = tid + p * 256;
                float v = lrelu_f(h2raw[(size_t)b * H2_DIM + j] * scl2[j] + shf2[j]);
                s += v * Wo[j];
            }
#pragma unroll
            for (int off = 32; off; off >>= 1) s += __shfl_down(s, off, 64);
            if (lane == 0) red[wave] = s;
            __syncthreads();
            if (tid == 0) out[b] = red[0] + red[1] + red[2] + red[3] + bo[0];
            __syncthreads();
        }
    }
}

// ================================================================ host
extern "C" void kernel_launch(void* const* d_in, const int* in_sizes, int n_in,
                              void* d_out, int out_size, void* d_ws, size_t ws_size,
                              hipStream_t stream) {
    const float* x     = (const float*)d_in[0];
    const float* Wg    = (const float*)d_in[1];
    const float* bg    = (const float*)d_in[2];
    const float* att_w = (const float*)d_in[3];
    const float* W1    = (const float*)d_in[4];
    const float* gamma1 = (const float*)d_in[6];
    const float* beta1  = (const float*)d_in[7];
    const float* W2    = (const float*)d_in[8];
    const float* gamma2 = (const float*)d_in[10];
    const float* beta2  = (const float*)d_in[11];
    const float* Wo    = (const float*)d_in[12];
    const float* bo    = (const float*)d_in[13];
    float* out = (float*)d_out;

    char* ws = (char*)d_ws;
    size_t off = 0;
    auto alloc = [&](size_t bytes) {
        void* p = ws + off;
        off = (off + bytes + 255) & ~(size_t)255;
        return p;
    };
    __hip_bfloat16* W1T   = (__hip_bfloat16*)alloc((size_t)H1_DIM * N_DIM * 2);
    __hip_bfloat16* W2T   = (__hip_bfloat16*)alloc((size_t)H2_DIM * H1_DIM * 2);
    __hip_bfloat16* g     = (__hip_bfloat16*)alloc((size_t)B_DIM * N_DIM * 2);
    __hip_bfloat16* h1pre = (__hip_bfloat16*)alloc((size_t)B_DIM * H1_DIM * 2);
    float*          h2raw = (float*)alloc((size_t)B_DIM * H2_DIM * 4);
    float*          ps1   = (float*)alloc(16 * H1_DIM * 4);
    float*          pq1   = (float*)alloc(16 * H1_DIM * 4);
    float*          ps2   = (float*)alloc(16 * H2_DIM * 4);
    float*          pq2   = (float*)alloc(16 * H2_DIM * 4);
    unsigned int*   cnts  = (unsigned int*)alloc(256);
    (void)ws_size; (void)in_sizes; (void)n_in; (void)out_size;

    // reset grid-barrier counters (stream-ordered, graph-capture legal, deterministic)
    hipMemsetAsync(cnts, 0, 8, stream);
    // 1. prep: group_linear (2048 blocks) + softmax/W1T (1024) + W2T (256)
    prep_kernel<<<dim3(2048 + 1024 + 256), 256, 0, stream>>>(x, Wg, bg, g,
                                                             W1, W2, att_w, W1T, W2T);
    // 2. fused: GEMM1+stats -> barrier -> GEMM2(+BN1)+stats -> barrier -> BN2+dot
    fused_main<<<dim3(512), 256, 0, stream>>>(g, W1T, W2T, h1pre, h2raw,
                                              ps1, pq1, ps2, pq2,
                                              gamma1, beta1, gamma2, beta2,
                                              Wo, bo, out, cnts);
}

// Round 11
// 104.656 us; speedup vs baseline: 3.6205x; 2.0644x over previous
//
#include <hip/hip_runtime.h>
#include <hip/hip_bf16.h>

#define B_DIM   1024
#define N_DIM   2048
#define G_DIM   32
#define H1_DIM  2048
#define H2_DIM  512
#define BN_EPS  1e-5f
#define SLOPE   0.05f

typedef short v8s __attribute__((ext_vector_type(8)));
typedef float v4f __attribute__((ext_vector_type(4)));

__device__ __forceinline__ float lrelu_f(float v) { return v >= 0.f ? v : SLOPE * v; }
__device__ __forceinline__ float bf2f(unsigned short u) {
    union { unsigned int i; float f; } c; c.i = ((unsigned int)u) << 16; return c.f;
}
__device__ __forceinline__ unsigned short f2bf(float f) {
    __hip_bfloat16 h = __float2bfloat16(f);
    return *(unsigned short*)&h;
}

// async global->LDS, 16B per lane, linear LDS dest (wave-uniform base + lane*16)
#define GLOAD_LDS16(gp, lp)                                                              \
    __builtin_amdgcn_global_load_lds(                                                    \
        (const __attribute__((address_space(1))) unsigned int*)(gp),                     \
        (__attribute__((address_space(3))) unsigned int*)(lp), 16, 0, 0)

// ================================================================ prep kernel
// Transposes FIRST so they overlap group_linear's HBM phase instead of tailing:
// bid < 1024          : W1 [N][H1] -> W1T [H1][N] bf16, rows scaled by softmax(att_w)
// 1024 <= bid < 1280  : W2 [H1][H2] -> W2T [H2][H1] bf16
// bid >= 1280         : group_linear  g[b][n] = lrelu(dot(x[b,n*32:], Wg[n]) + bg[n])
__global__ __launch_bounds__(256) void prep_kernel(
        const float* __restrict__ x, const float* __restrict__ Wg,
        const float* __restrict__ bg, __hip_bfloat16* __restrict__ g,
        const float* __restrict__ W1, const float* __restrict__ W2,
        const float* __restrict__ aw,
        __hip_bfloat16* __restrict__ W1T, __hip_bfloat16* __restrict__ W2T) {
    __shared__ float tile[64][65];
    __shared__ float red[8];
    __shared__ float scl[64];
    int t = threadIdx.x;
    int bid = blockIdx.x;

    if (bid >= 1280) {
        // ---------------- group_linear: 2 lanes per group, coalesced x reads
        int bid2 = bid - 1280;
        int brow = bid2 >> 4;             // 128 brows x 8 batch rows
        int seg = bid2 & 15;              // 16 segs x 128 groups
        int gl = t >> 1, half = t & 1;
        int n = seg * 128 + gl;
        float4 wv[4];
        const float4* wsrc = (const float4*)(Wg + (size_t)n * 32 + half * 16);
#pragma unroll
        for (int q = 0; q < 4; ++q) wv[q] = wsrc[q];
        float bgv = bg[n];
#pragma unroll
        for (int bb = 0; bb < 8; ++bb) {
            int b = brow * 8 + bb;
            const float4* xr = (const float4*)(x + (size_t)b * (N_DIM * G_DIM) +
                                               (size_t)n * 32 + half * 16);
            float s = 0.f;
#pragma unroll
            for (int q = 0; q < 4; ++q) {
                float4 v = xr[q];
                s += v.x * wv[q].x + v.y * wv[q].y + v.z * wv[q].z + v.w * wv[q].w;
            }
            s += __shfl_xor(s, 1, 64);
            if (half == 0)
                g[(size_t)b * N_DIM + n] = __float2bfloat16(lrelu_f(s + bgv));
        }
        return;
    }

    // ---------------- transposes
    const float* W;
    __hip_bfloat16* Wt;
    int Kd, Jd, j0, k0;
    bool doScale;
    if (bid < 1024) {
        W = W1; Wt = W1T; Kd = N_DIM; Jd = H1_DIM;
        j0 = (bid & 31) * 64; k0 = (bid >> 5) * 64; doScale = true;
        // block-redundant softmax over att_w[0..2047]
        float mx = -1e30f;
#pragma unroll
        for (int i = 0; i < 8; ++i) mx = fmaxf(mx, aw[t + i * 256]);
#pragma unroll
        for (int off = 32; off; off >>= 1) mx = fmaxf(mx, __shfl_xor(mx, off, 64));
        if ((t & 63) == 0) red[t >> 6] = mx;
        __syncthreads();
        float M = fmaxf(fmaxf(red[0], red[1]), fmaxf(red[2], red[3]));
        float sm = 0.f;
#pragma unroll
        for (int i = 0; i < 8; ++i) sm += expf(aw[t + i * 256] - M);
#pragma unroll
        for (int off = 32; off; off >>= 1) sm += __shfl_xor(sm, off, 64);
        if ((t & 63) == 0) red[4 + (t >> 6)] = sm;
        __syncthreads();
        float invS = 1.f / (red[4] + red[5] + red[6] + red[7]);
        if (t < 64) scl[t] = expf(aw[k0 + t] - M) * invS;
        __syncthreads();
    } else {
        int b2 = bid - 1024;
        W = W2; Wt = W2T; Kd = H1_DIM; Jd = H2_DIM;
        j0 = (b2 & 7) * 64; k0 = (b2 >> 3) * 64; doScale = false;
    }
#pragma unroll
    for (int p = 0; p < 16; ++p) {
        int r = (t >> 6) + p * 4;
        float v = W[(size_t)(k0 + r) * Jd + j0 + (t & 63)];
        if (doScale) v *= scl[r];
        tile[r][t & 63] = v;
    }
    __syncthreads();
#pragma unroll
    for (int p = 0; p < 8; ++p) {
        int jr = (t >> 5) + p * 8;
        int kc = (t & 31) * 2;
        ushort2 pk;
        pk.x = f2bf(tile[kc][jr]);
        pk.y = f2bf(tile[kc + 1][jr]);
        *(ushort2*)(Wt + (size_t)(j0 + jr) * Kd + k0 + kc) = pk;
    }
}

// ================================================================ GEMM1 (+BN1 stats)
// Proven config: 64x64 tile, 4 waves, BK=128, grid 512 -> 2 blocks/CU.
// XOR-swizzled LDS (chunk^(row&15)), setprio around MFMA, XCD-chunk block swizzle.
__global__ __launch_bounds__(256) void gemm1_stats(
        const __hip_bfloat16* __restrict__ A, const __hip_bfloat16* __restrict__ Bt,
        __hip_bfloat16* __restrict__ C, float* __restrict__ ps, float* __restrict__ pq) {
    __shared__ __hip_bfloat16 A_s[2][64 * 128];
    __shared__ __hip_bfloat16 B_s[2][64 * 128];
    __shared__ float rs[2][64], rq[2][64];

    int bid = blockIdx.x;                       // 512 blocks
    int wg  = (bid & 7) * 64 + (bid >> 3);      // XCD-aware bijective swizzle
    int bx  = wg & 15, by = wg >> 4;            // 16 row-tiles x 32 col-tiles

    int tid = threadIdx.x, lane = tid & 63, wave = tid >> 6;
    int wr = wave >> 1, wc = wave & 1;
    int rbase = bx * 64, cbase = by * 64;
    int l15 = lane & 15, kq = lane >> 4;

    v4f acc[2][2] = {};

    auto stage = [&](int buf, int kt) {
        int k0 = kt << 7;
#pragma unroll
        for (int i = 0; i < 4; ++i) {
            int s = tid + i * 256;
            int row = s >> 4, cg = (s & 15) ^ (row & 15);
            GLOAD_LDS16(A + (size_t)(rbase + row) * N_DIM + k0 + cg * 8,
                        (char*)A_s[buf] + s * 16);
        }
#pragma unroll
        for (int i = 0; i < 4; ++i) {
            int s = tid + i * 256;
            int row = s >> 4, cg = (s & 15) ^ (row & 15);
            GLOAD_LDS16(Bt + (size_t)(cbase + row) * N_DIM + k0 + cg * 8,
                        (char*)B_s[buf] + s * 16);
        }
    };

    stage(0, 0);
    __syncthreads();
    int cur = 0;
    for (int kt = 0; kt < 16; ++kt) {
        if (kt + 1 < 16) stage(cur ^ 1, kt + 1);
#pragma unroll
        for (int kc = 0; kc < 4; ++kc) {
            v8s af[2], bfv[2];
#pragma unroll
            for (int m = 0; m < 2; ++m) {
                int row = wr * 32 + m * 16 + l15;
                int off = row * 256 + (((kc * 4 + kq) ^ (row & 15)) << 4);
                af[m] = *(const v8s*)((const char*)A_s[cur] + off);
            }
#pragma unroll
            for (int n = 0; n < 2; ++n) {
                int row = wc * 32 + n * 16 + l15;
                int off = row * 256 + (((kc * 4 + kq) ^ (row & 15)) << 4);
                bfv[n] = *(const v8s*)((const char*)B_s[cur] + off);
            }
            __builtin_amdgcn_s_setprio(1);
#pragma unroll
            for (int m = 0; m < 2; ++m)
#pragma unroll
                for (int n = 0; n < 2; ++n)
                    acc[m][n] = __builtin_amdgcn_mfma_f32_16x16x32_bf16(af[m], bfv[n],
                                                                        acc[m][n], 0, 0, 0);
            __builtin_amdgcn_s_setprio(0);
        }
        __syncthreads();
        cur ^= 1;
    }

    int crow = kq * 4;
#pragma unroll
    for (int m = 0; m < 2; ++m)
#pragma unroll
        for (int n = 0; n < 2; ++n) {
            int r = rbase + wr * 32 + m * 16 + crow;
            int c = cbase + wc * 32 + n * 16 + l15;
#pragma unroll
            for (int i = 0; i < 4; ++i)
                C[(size_t)(r + i) * H1_DIM + c] = __float2bfloat16(acc[m][n][i]);
        }

    float cs[2], cq[2];
#pragma unroll
    for (int n = 0; n < 2; ++n) {
        cs[n] = 0.f; cq[n] = 0.f;
#pragma unroll
        for (int m = 0; m < 2; ++m)
#pragma unroll
            for (int i = 0; i < 4; ++i) {
                float v = acc[m][n][i];
                cs[n] += v; cq[n] += v * v;
            }
#pragma unroll
        for (int off = 16; off <= 32; off <<= 1) {
            cs[n] += __shfl_xor(cs[n], off, 64);
            cq[n] += __shfl_xor(cq[n], off, 64);
        }
    }
    if (lane < 16) {
#pragma unroll
        for (int n = 0; n < 2; ++n) {
            rs[wr][wc * 32 + n * 16 + lane] = cs[n];
            rq[wr][wc * 32 + n * 16 + lane] = cq[n];
        }
    }
    __syncthreads();
    if (tid < 64) {
        ps[(size_t)bx * H1_DIM + cbase + tid] = rs[0][tid] + rs[1][tid];
        pq[(size_t)bx * H1_DIM + cbase + tid] = rq[0][tid] + rq[1][tid];
    }
}

// ================================================================ GEMM2 with BN1 folded
// 64x32 tile, 4 waves (each 16 rows x 32 cols), BK=128, grid 256 blocks.
// Prologue: block-redundant BN1 finalize from ps1/pq1 -> scl/shf[2048] in LDS.
// A-staging: reg-load h1pre bf16, apply scale/shift+lrelu, bf16, swizzled ds_write.
// B-staging: global_load_lds. Epilogue: BN2 partial stats.
__global__ __launch_bounds__(256) void gemm2_bn1(
        const __hip_bfloat16* __restrict__ h1pre, const __hip_bfloat16* __restrict__ W2T,
        float* __restrict__ h2raw,
        const float* __restrict__ ps1, const float* __restrict__ pq1,
        const float* __restrict__ gamma1, const float* __restrict__ beta1,
        float* __restrict__ ps2, float* __restrict__ pq2) {
    __shared__ float scl[H1_DIM], shf[H1_DIM];
    __shared__ __hip_bfloat16 A2[2][64 * 128];
    __shared__ __hip_bfloat16 B2[2][32 * 128];
    __shared__ float rs2[4][32], rq2[4][32];

    int tid = threadIdx.x, lane = tid & 63, wave = tid >> 6;
    int l15 = lane & 15, kq = lane >> 4;

    // BN1 finalize (block-redundant, 8 cols/thread from 16 partials)
#pragma unroll
    for (int p = 0; p < 8; ++p) {
        int c = tid + p * 256;
        float s = 0.f, q = 0.f;
#pragma unroll
        for (int i = 0; i < 16; ++i) {
            s += ps1[i * H1_DIM + c];
            q += pq1[i * H1_DIM + c];
        }
        float mu = s * (1.f / B_DIM);
        float var = fmaxf(q * (1.f / B_DIM) - mu * mu, 0.f);
        float rsv = rsqrtf(var + BN_EPS);
        float sc = rsv * gamma1[c];
        scl[c] = sc;
        shf[c] = beta1[c] - mu * sc;
    }
    __syncthreads();

    int bid = blockIdx.x;
    int wg = (bid & 7) * 32 + (bid >> 3);       // XCD swizzle, 256 blocks
    int bxx = wg & 15, byy = wg >> 4;           // 16 row-tiles x 16 col-tiles
    int rb = bxx * 64, cb = byy * 32;

    v4f acc2[2] = {};

    auto stageA2 = [&](int buf, int kt) {       // reg-staged + BN+lrelu + swizzled ds_write
        int k0 = kt << 7;
#pragma unroll
        for (int i = 0; i < 4; ++i) {
            int s = tid + i * 256;
            int row = s >> 4, cc = s & 15;
            v8s hv = *(const v8s*)(h1pre + (size_t)(rb + row) * H1_DIM + k0 + cc * 8);
            int kk = k0 + cc * 8;
            float4 s0 = *(const float4*)&scl[kk];
            float4 s1 = *(const float4*)&scl[kk + 4];
            float4 f0 = *(const float4*)&shf[kk];
            float4 f1 = *(const float4*)&shf[kk + 4];
            v8s pk;
            pk[0] = (short)f2bf(lrelu_f(bf2f((unsigned short)hv[0]) * s0.x + f0.x));
            pk[1] = (short)f2bf(lrelu_f(bf2f((unsigned short)hv[1]) * s0.y + f0.y));
            pk[2] = (short)f2bf(lrelu_f(bf2f((unsigned short)hv[2]) * s0.z + f0.z));
            pk[3] = (short)f2bf(lrelu_f(bf2f((unsigned short)hv[3]) * s0.w + f0.w));
            pk[4] = (short)f2bf(lrelu_f(bf2f((unsigned short)hv[4]) * s1.x + f1.x));
            pk[5] = (short)f2bf(lrelu_f(bf2f((unsigned short)hv[5]) * s1.y + f1.y));
            pk[6] = (short)f2bf(lrelu_f(bf2f((unsigned short)hv[6]) * s1.z + f1.z));
            pk[7] = (short)f2bf(lrelu_f(bf2f((unsigned short)hv[7]) * s1.w + f1.w));
            *(v8s*)((char*)A2[buf] + (row * 16 + (cc ^ (row & 15))) * 16) = pk;
        }
    };
    auto stageB2 = [&](int buf, int kt) {
        int k0 = kt << 7;
#pragma unroll
        for (int i = 0; i < 2; ++i) {
            int s = tid + i * 256;
            int row = s >> 4, cg2 = (s & 15) ^ (row & 15);
            GLOAD_LDS16(W2T + (size_t)(cb + row) * H1_DIM + k0 + cg2 * 8,
                        (char*)B2[buf] + s * 16);
        }
    };

    stageB2(0, 0);
    stageA2(0, 0);
    __syncthreads();
    int cur = 0;
    for (int kt = 0; kt < 16; ++kt) {
        if (kt + 1 < 16) { stageB2(cur ^ 1, kt + 1); stageA2(cur ^ 1, kt + 1); }
#pragma unroll
        for (int kc = 0; kc < 4; ++kc) {
            int arow = wave * 16 + l15;
            v8s af = *(const v8s*)((const char*)A2[cur] +
                                   arow * 256 + (((kc * 4 + kq) ^ (arow & 15)) << 4));
            v8s bf0 = *(const v8s*)((const char*)B2[cur] +
                                    l15 * 256 + (((kc * 4 + kq) ^ (l15 & 15)) << 4));
            int brow1 = 16 + l15;
            v8s bf1 = *(const v8s*)((const char*)B2[cur] +
                                    brow1 * 256 + (((kc * 4 + kq) ^ (brow1 & 15)) << 4));
            __builtin_amdgcn_s_setprio(1);
            acc2[0] = __builtin_amdgcn_mfma_f32_16x16x32_bf16(af, bf0, acc2[0], 0, 0, 0);
            acc2[1] = __builtin_amdgcn_mfma_f32_16x16x32_bf16(af, bf1, acc2[1], 0, 0, 0);
            __builtin_amdgcn_s_setprio(0);
        }
        __syncthreads();
        cur ^= 1;
    }

    int crow = kq * 4;
#pragma unroll
    for (int n = 0; n < 2; ++n) {
        int r = rb + wave * 16 + crow;
        int c = cb + n * 16 + l15;
#pragma unroll
        for (int i = 0; i < 4; ++i)
            h2raw[(size_t)(r + i) * H2_DIM + c] = acc2[n][i];
    }

    float cs[2], cq[2];
#pragma unroll
    for (int n = 0; n < 2; ++n) {
        cs[n] = 0.f; cq[n] = 0.f;
#pragma unroll
        for (int i = 0; i < 4; ++i) {
            float v = acc2[n][i];
            cs[n] += v; cq[n] += v * v;
        }
#pragma unroll
        for (int off = 16; off <= 32; off <<= 1) {
            cs[n] += __shfl_xor(cs[n], off, 64);
            cq[n] += __shfl_xor(cq[n], off, 64);
        }
    }
    if (lane < 16) {
#pragma unroll
        for (int n = 0; n < 2; ++n) {
            rs2[wave][n * 16 + lane] = cs[n];
            rq2[wave][n * 16 + lane] = cq[n];
        }
    }
    __syncthreads();
    if (tid < 32) {
        float s = 0.f, q = 0.f;
#pragma unroll
        for (int w = 0; w < 4; ++w) { s += rs2[w][tid]; q += rq2[w][tid]; }
        ps2[(size_t)bxx * H2_DIM + cb + tid] = s;
        pq2[(size_t)bxx * H2_DIM + cb + tid] = q;
    }
}

// ------------------------------------------------ BN2 finalize (block-redundant) + lrelu + dot(Wo)+bo
__global__ __launch_bounds__(256) void bn_dot_fused(
        const float* __restrict__ h2,
        const float* __restrict__ ps, const float* __restrict__ pq,
        const float* __restrict__ gamma, const float* __restrict__ beta,
        const float* __restrict__ Wo, const float* __restrict__ bo,
        float* __restrict__ out) {
    __shared__ float scl[H2_DIM], shf[H2_DIM];
    __shared__ float red[4][4];
    int t = threadIdx.x;
#pragma unroll
    for (int p = 0; p < 2; ++p) {
        int c = t + p * 256;
        float s = 0.f, q = 0.f;
#pragma unroll
        for (int i = 0; i < 16; ++i) {
            s += ps[i * H2_DIM + c];
            q += pq[i * H2_DIM + c];
        }
        float mu = s * (1.f / B_DIM);
        float var = fmaxf(q * (1.f / B_DIM) - mu * mu, 0.f);
        float rsv = rsqrtf(var + BN_EPS);
        float sc = rsv * gamma[c];
        scl[c] = sc;
        shf[c] = beta[c] - mu * sc;
    }
    __syncthreads();
    float accv[4];
#pragma unroll
    for (int r = 0; r < 4; ++r) {
        int b = blockIdx.x * 4 + r;
        float s = 0.f;
#pragma unroll
        for (int p = 0; p < 2; ++p) {
            int jj = t + p * 256;
            float v = lrelu_f(h2[(size_t)b * H2_DIM + jj] * scl[jj] + shf[jj]);
            s += v * Wo[jj];
        }
#pragma unroll
        for (int off = 32; off; off >>= 1) s += __shfl_down(s, off, 64);
        accv[r] = s;
    }
    if ((t & 63) == 0) {
#pragma unroll
        for (int r = 0; r < 4; ++r) red[t >> 6][r] = accv[r];
    }
    __syncthreads();
    if (t < 4)
        out[blockIdx.x * 4 + t] = red[0][t] + red[1][t] + red[2][t] + red[3][t] + bo[0];
}

// ================================================================ host
extern "C" void kernel_launch(void* const* d_in, const int* in_sizes, int n_in,
                              void* d_out, int out_size, void* d_ws, size_t ws_size,
                              hipStream_t stream) {
    const float* x     = (const float*)d_in[0];
    const float* Wg    = (const float*)d_in[1];
    const float* bg    = (const float*)d_in[2];
    const float* att_w = (const float*)d_in[3];
    const float* W1    = (const float*)d_in[4];
    const float* gamma1 = (const float*)d_in[6];
    const float* beta1  = (const float*)d_in[7];
    const float* W2    = (const float*)d_in[8];
    const float* gamma2 = (const float*)d_in[10];
    const float* beta2  = (const float*)d_in[11];
    const float* Wo    = (const float*)d_in[12];
    const float* bo    = (const float*)d_in[13];
    float* out = (float*)d_out;

    char* ws = (char*)d_ws;
    size_t off = 0;
    auto alloc = [&](size_t bytes) {
        void* p = ws + off;
        off = (off + bytes + 255) & ~(size_t)255;
        return p;
    };
    __hip_bfloat16* W1T   = (__hip_bfloat16*)alloc((size_t)H1_DIM * N_DIM * 2);
    __hip_bfloat16* W2T   = (__hip_bfloat16*)alloc((size_t)H2_DIM * H1_DIM * 2);
    __hip_bfloat16* g     = (__hip_bfloat16*)alloc((size_t)B_DIM * N_DIM * 2);
    __hip_bfloat16* h1pre = (__hip_bfloat16*)alloc((size_t)B_DIM * H1_DIM * 2);
    float*          h2raw = (float*)alloc((size_t)B_DIM * H2_DIM * 4);
    float*          ps1   = (float*)alloc(16 * H1_DIM * 4);
    float*          pq1   = (float*)alloc(16 * H1_DIM * 4);
    float*          ps2   = (float*)alloc(16 * H2_DIM * 4);
    float*          pq2   = (float*)alloc(16 * H2_DIM * 4);
    (void)ws_size; (void)in_sizes; (void)n_in; (void)out_size;

    // 1. prep: softmax/W1T (blocks 0-1023) + W2T (1024-1279) + group_linear (1280-3327)
    prep_kernel<<<dim3(1280 + 2048), 256, 0, stream>>>(x, Wg, bg, g,
                                                       W1, W2, att_w, W1T, W2T);
    // 2. GEMM1 (+BN1 stats): h1pre = bf16(g @ (att*W1)), 64x64 tiles, 512 blocks
    gemm1_stats<<<dim3(512), 256, 0, stream>>>(g, W1T, h1pre, ps1, pq1);
    // 3. GEMM2 with BN1 finalize+apply+lrelu folded into A-staging (+BN2 stats)
    gemm2_bn1<<<dim3(256), 256, 0, stream>>>(h1pre, W2T, h2raw, ps1, pq1,
                                             gamma1, beta1, ps2, pq2);
    // 4. BN2 finalize + lrelu + dot(Wo) + bo -> out [B]
    bn_dot_fused<<<dim3(B_DIM / 4), 256, 0, stream>>>(h2raw, ps2, pq2, gamma2, beta2,
                                                      Wo, bo, out);
}